// Round 18
// baseline (292.270 us; speedup 1.0000x reference)
//
#include <hip/hip_runtime.h>
#include <hip/hip_bf16.h>
#include <cstdint>
#include <cstddef>

typedef __bf16 bf16;
typedef __bf16 bf16x2 __attribute__((ext_vector_type(2)));
typedef __bf16 bf16x4 __attribute__((ext_vector_type(4)));
typedef __bf16 bf16x8 __attribute__((ext_vector_type(8)));
typedef float  f32x4  __attribute__((ext_vector_type(4)));

#define HIDDEN 2048
#define NHEADS 16
#define NKV    4
#define HD     128
#define WINDOW 512
#define NLT    -0.14390747054172642f   // -ln(10000)/64

// async global->LDS, 16B per lane; LDS dest is wave-uniform base + lane*16
__device__ __forceinline__ void gld16(const void* g, void* s) {
  __builtin_amdgcn_global_load_lds((const __attribute__((address_space(1))) void*)g,
                                   (__attribute__((address_space(3))) void*)s, 16, 0, 0);
}

__device__ __forceinline__ f32x4 mfma16(bf16x8 a, bf16x8 b, f32x4 c) {
  return __builtin_amdgcn_mfma_f32_16x16x32_bf16(a, b, c, 0, 0, 0);
}

__device__ __forceinline__ void barrier_raw() {
  asm volatile("" ::: "memory");
  __builtin_amdgcn_s_barrier();
  asm volatile("" ::: "memory");
}

// ---------------- cast fp32 -> bf16, 8 elems/thread -------------------------
__global__ __launch_bounds__(256) void cast_f32_bf16(const float* __restrict__ in,
                                                     bf16* __restrict__ out, int n8) {
  int i = blockIdx.x * 256 + threadIdx.x;
  if (i >= n8) return;
  f32x4 a = *(const f32x4*)(in + (size_t)i * 8);
  f32x4 b = *(const f32x4*)(in + (size_t)i * 8 + 4);
  bf16x8 o;
  #pragma unroll
  for (int k = 0; k < 4; ++k) { o[k] = (bf16)a[k]; o[k + 4] = (bf16)b[k]; }
  *(bf16x8*)(out + (size_t)i * 8) = o;
}

// ------- transpose+cast, 2 matrices per launch (blockIdx.z selects) ---------
__global__ __launch_bounds__(256) void transpose_cast2(const float* __restrict__ in0,
                                                       bf16* __restrict__ out0,
                                                       const float* __restrict__ in1,
                                                       bf16* __restrict__ out1,
                                                       int R, int C) {
  const float* in = blockIdx.z ? in1 : in0;
  bf16* out       = blockIdx.z ? out1 : out0;
  __shared__ float tile[32][33];
  int c0 = blockIdx.x * 32, r0 = blockIdx.y * 32;
  int tx = threadIdx.x, ty = threadIdx.y;
  #pragma unroll
  for (int i = 0; i < 4; ++i)
    tile[ty + i * 8][tx] = in[(size_t)(r0 + ty + i * 8) * C + c0 + tx];
  __syncthreads();
  #pragma unroll
  for (int i = 0; i < 4; ++i)
    out[(size_t)(c0 + ty + i * 8) * R + r0 + tx] = (bf16)tile[tx][ty + i * 8];
}

// ===== 128x128 GEMM, BK=64, swizzled LDS (merged K+V projection) ============
__device__ __forceinline__ void stage128x64(const bf16* __restrict__ A,
                                            const bf16* __restrict__ Bt,
                                            bf16* sA, bf16* sB,
                                            int m0, int n0, int K, int kt, int tid) {
  int wb = (tid & ~63) * 8;
  #pragma unroll
  for (int r = 0; r < 4; ++r) {
    int n = r * 256 + tid;                   // chunk id 0..1023
    int row = n >> 3;
    int c = (n & 7) ^ (row & 7);             // inverse-swizzled source chunk
    gld16(A  + (size_t)(m0 + row) * K + (size_t)kt * 64 + c * 8,
          sA + (size_t)(r * 256 * 8) + wb);
    gld16(Bt + (size_t)(n0 + row) * K + (size_t)kt * 64 + c * 8,
          sB + (size_t)(r * 256 * 8) + wb);
  }
}

// outMode: 0 bf16 row-major; 1 bf16 C^T; 2 fp32 row-major;
//          3 merged KV+RoPE: col<512 -> K row-major with RoPE; else V^T
__global__ __launch_bounds__(256) void gemm_bt(const bf16* __restrict__ A,
                                               const bf16* __restrict__ Bt,
                                               void* __restrict__ Cv,
                                               bf16* __restrict__ Vtout,
                                               const int* __restrict__ pos,
                                               int M, int N, int K, int outMode) {
  __shared__ bf16 sA[2][128 * 64];           // 32 KB
  __shared__ bf16 sB[2][128 * 64];           // 32 KB
  int nb = N >> 7;
  int perx = (int)gridDim.x >> 3;            // grid must be a multiple of 8
  int bid0 = (int)blockIdx.x;
  int swzb = (bid0 & 7) * perx + (bid0 >> 3);
  int bm = swzb / nb, bn = swzb % nb;
  int m0 = bm << 7, n0 = bn << 7;
  int tid = threadIdx.x;
  int lane = tid & 63, w = tid >> 6;
  int li = lane & 15, g = lane >> 4;
  int wm = w >> 1, wn = w & 1;
  int swz = li & 7;
  f32x4 acc[4][4] = {};
  int NT = K >> 6;                           // 32

  stage128x64(A, Bt, sA[0], sB[0], m0, n0, K, 0, tid);
  for (int kt = 0; kt < NT; ++kt) {
    int cur = kt & 1;
    asm volatile("s_waitcnt vmcnt(0)" ::: "memory");   // own tile-kt loads
    barrier_raw();                                      // publish to all waves
    if (kt + 1 < NT)
      stage128x64(A, Bt, sA[cur ^ 1], sB[cur ^ 1], m0, n0, K, kt + 1, tid);
    bf16x8 af[4][2], bv[4][2];
    #pragma unroll
    for (int mt = 0; mt < 4; ++mt)
      #pragma unroll
      for (int ks = 0; ks < 2; ++ks)
        af[mt][ks] = *(const bf16x8*)&sA[cur][(wm * 64 + mt * 16 + li) * 64
                                              + ((ks * 4 + g) ^ swz) * 8];
    #pragma unroll
    for (int nt = 0; nt < 4; ++nt)
      #pragma unroll
      for (int ks = 0; ks < 2; ++ks)
        bv[nt][ks] = *(const bf16x8*)&sB[cur][(wn * 64 + nt * 16 + li) * 64
                                              + ((ks * 4 + g) ^ swz) * 8];
    #pragma unroll
    for (int mt = 0; mt < 4; ++mt)
      #pragma unroll
      for (int nt = 0; nt < 4; ++nt)
        #pragma unroll
        for (int ks = 0; ks < 2; ++ks)
          acc[mt][nt] = mfma16(af[mt][ks], bv[nt][ks], acc[mt][nt]);
  }
  if (outMode == 3 && n0 >= 512) {
    // V^T region: j-vectorized 8B stores (row0 multiple of 4 -> aligned)
    #pragma unroll
    for (int mt = 0; mt < 4; ++mt)
      #pragma unroll
      for (int nt = 0; nt < 4; ++nt) {
        int row0 = m0 + wm * 64 + mt * 16 + g * 4;
        int col = n0 + wn * 64 + nt * 16 + li;
        bf16x4 vv;
        #pragma unroll
        for (int j = 0; j < 4; ++j) vv[j] = (bf16)acc[mt][nt][j];
        *(bf16x4*)&Vtout[(size_t)(col - 512) * M + row0] = vv;
      }
  } else if (outMode == 3) {
    // K region with fused RoPE; paired bf16x2 stores (even lanes, 4B)
    #pragma unroll
    for (int mt = 0; mt < 4; ++mt)
      #pragma unroll
      for (int nt = 0; nt < 4; ++nt)
        #pragma unroll
        for (int j = 0; j < 4; ++j) {
          int row = m0 + wm * 64 + mt * 16 + g * 4 + j;
          int col = n0 + wn * 64 + nt * 16 + li;
          float v = acc[mt][nt][j];
          float inv = __expf((float)((col & 127) >> 1) * NLT);
          float ang = (float)pos[row] * inv;
          float s = __sinf(ang), c = __cosf(ang);
          float pv = __shfl_xor(v, 1);
          float outv = (li & 1) ? (pv * s + v * c) : (v * c - pv * s);
          float po = __shfl_xor(outv, 1);
          if (!(lane & 1)) {
            bf16x2 t2; t2[0] = (bf16)outv; t2[1] = (bf16)po;
            *(bf16x2*)&((bf16*)Cv)[(size_t)row * 512 + col] = t2;
          }
        }
  } else {
    #pragma unroll
    for (int mt = 0; mt < 4; ++mt)
      #pragma unroll
      for (int nt = 0; nt < 4; ++nt)
        #pragma unroll
        for (int j = 0; j < 4; ++j) {
          int row = m0 + wm * 64 + mt * 16 + g * 4 + j;
          int col = n0 + wn * 64 + nt * 16 + li;
          float v = acc[mt][nt][j];
          if (outMode == 0)      ((bf16*)Cv)[(size_t)row * N + col] = (bf16)v;
          else if (outMode == 1) ((bf16*)Cv)[(size_t)col * M + row] = (bf16)v;
          else                   ((float*)Cv)[(size_t)row * N + col] = v;
        }
  }
}

// ============== 256x256 8-wave GEMM (round-7 variant, early-stage issue) ====
template<int RSP>  // 64 for A halves, 32 for B halves
__device__ __forceinline__ void stage_quad(const bf16* __restrict__ G,
                                           bf16* __restrict__ sbuf,
                                           int grow0, int K, int k0, int half, int tid) {
  int w = tid >> 6, lane = tid & 63;
  int rl = lane >> 3;
  int col = ((lane & 7) ^ rl) * 8;            // inverse-swizzled SOURCE col (rule #21)
  #pragma unroll
  for (int r = 0; r < 2; ++r) {
    int lr0 = r * 64 + w * 8;
    int row0 = (lr0 & (RSP - 1)) + half * RSP + (lr0 / RSP) * 2 * RSP;
    gld16(G + (size_t)(grow0 + row0 + rl) * K + k0 + col,
          sbuf + row0 * 64);
  }
}

// outMode: 0 bf16; 2 fp32; 3 bf16 + fused interleaved RoPE (Q projection)
__global__ __launch_bounds__(512, 2) void gemm256(const bf16* __restrict__ A,
                                                  const bf16* __restrict__ Bt,
                                                  void* __restrict__ Cv,
                                                  const int* __restrict__ pos,
                                                  int M, int N, int K, int outMode) {
  __shared__ bf16 sA[2][256 * 64];
  __shared__ bf16 sB[2][256 * 64];
  int nb = N >> 8;
  int cpx = (int)gridDim.x >> 3;
  int bid = (int)blockIdx.x;
  int swzb = (bid & 7) * cpx + (bid >> 3);
  int bm = swzb / nb, bn = swzb % nb;
  int m0 = bm << 8, n0 = bn << 8;
  int tid = threadIdx.x, lane = tid & 63, w = tid >> 6;
  int li = lane & 15, g = lane >> 4;
  int wm = w >> 2, wn = w & 3;
  int swz = (li & 7);

  f32x4 acc[8][4] = {};
  bf16x8 af[4][2];
  bf16x8 bv[2][2][2];

  int NT = K >> 6;

  stage_quad<64>(A,  sA[0], m0, K, 0, 0, tid);
  stage_quad<32>(Bt, sB[0], n0, K, 0, 0, tid);
  stage_quad<32>(Bt, sB[0], n0, K, 0, 1, tid);
  stage_quad<64>(A,  sA[0], m0, K, 0, 1, tid);

#define VMW(n) asm volatile("s_waitcnt vmcnt(" #n ")" ::: "memory")
#define SBAR() __builtin_amdgcn_sched_barrier(0)
#define LGKM(n) { asm volatile("s_waitcnt lgkmcnt(" #n ")" ::: "memory"); \
  __builtin_amdgcn_sched_barrier(0); }
#define LOAD_A256(mh) { _Pragma("unroll") for (int mf = 0; mf < 4; ++mf) \
  _Pragma("unroll") for (int ks = 0; ks < 2; ++ks) { \
    int row = wm * 128 + (mh) * 64 + mf * 16 + li; \
    af[mf][ks] = *(const bf16x8*)&sA[cur][row * 64 + ((ks * 4 + g) ^ swz) * 8]; } }
#define LOAD_B256(nh) { _Pragma("unroll") for (int nf = 0; nf < 2; ++nf) \
  _Pragma("unroll") for (int ks = 0; ks < 2; ++ks) { \
    int row = wn * 64 + (nh) * 32 + nf * 16 + li; \
    bv[nh][nf][ks] = *(const bf16x8*)&sB[cur][row * 64 + ((ks * 4 + g) ^ swz) * 8]; } }
#define MFMA_PH(mh, nh) { \
  __builtin_amdgcn_s_setprio(1); \
  _Pragma("unroll") for (int mf = 0; mf < 4; ++mf) \
  _Pragma("unroll") for (int nf = 0; nf < 2; ++nf) \
  _Pragma("unroll") for (int ks = 0; ks < 2; ++ks) \
    acc[(mh) * 4 + mf][(nh) * 2 + nf] = \
      mfma16(af[mf][ks], bv[nh][nf][ks], acc[(mh) * 4 + mf][(nh) * 2 + nf]); \
  __builtin_amdgcn_s_setprio(0); }

  int cur = 0;
  for (int t = 0; t < NT; ++t) {
    int nxt = cur ^ 1;
    bool pre = (t + 1 < NT);
    int k1 = (t + 1) << 6;
    VMW(0);
    barrier_raw();
    // all 4 stages issued immediately: youngest load gets a full tile body
    // (~1500 cyc) of slack before the next VMW(0) -> covers HBM latency.
    if (pre) {
      stage_quad<64>(A,  sA[nxt], m0, K, k1, 0, tid);
      stage_quad<32>(Bt, sB[nxt], n0, K, k1, 0, tid);
      stage_quad<32>(Bt, sB[nxt], n0, K, k1, 1, tid);
      stage_quad<64>(A,  sA[nxt], m0, K, k1, 1, tid);
    }
    LOAD_A256(0); LOAD_B256(0);
    SBAR();
    LOAD_B256(1);
    LGKM(4);
    MFMA_PH(0, 0);
    LGKM(0);
    MFMA_PH(0, 1);
    LOAD_A256(1);
    LGKM(0);
    MFMA_PH(1, 1);
    MFMA_PH(1, 0);
    cur = nxt;
  }
#undef VMW
#undef SBAR
#undef LGKM
#undef LOAD_A256
#undef LOAD_B256
#undef MFMA_PH

  if (outMode == 3) {
    // fused interleaved RoPE; __sinf/__cosf return-by-value (r10 lesson);
    // paired bf16x2 stores (even lanes) avoid 2x write amplification.
    float inv4[4];
    #pragma unroll
    for (int ni = 0; ni < 4; ++ni) {
      int col = n0 + wn * 64 + ni * 16 + li;
      inv4[ni] = __expf((float)((col & 127) >> 1) * NLT);
    }
    #pragma unroll
    for (int mi = 0; mi < 8; ++mi)
      #pragma unroll
      for (int j = 0; j < 4; ++j) {
        int row = m0 + wm * 128 + mi * 16 + g * 4 + j;
        float pr = (float)pos[row];
        #pragma unroll
        for (int ni = 0; ni < 4; ++ni) {
          int col = n0 + wn * 64 + ni * 16 + li;
          float ang = pr * inv4[ni];
          float s = __sinf(ang), c = __cosf(ang);
          float v = acc[mi][ni][j];
          float pv = __shfl_xor(v, 1);
          float outv = (li & 1) ? (pv * s + v * c) : (v * c - pv * s);
          float po = __shfl_xor(outv, 1);
          if (!(lane & 1)) {
            bf16x2 t2; t2[0] = (bf16)outv; t2[1] = (bf16)po;
            *(bf16x2*)&((bf16*)Cv)[(size_t)row * N + col] = t2;
          }
        }
      }
  } else {
    #pragma unroll
    for (int mi = 0; mi < 8; ++mi)
      #pragma unroll
      for (int ni = 0; ni < 4; ++ni)
        #pragma unroll
        for (int j = 0; j < 4; ++j) {
          int row = m0 + wm * 128 + mi * 16 + g * 4 + j;
          int col = n0 + wn * 64 + ni * 16 + li;
          float v = acc[mi][ni][j];
          if (outMode == 2) ((float*)Cv)[(size_t)row * N + col] = v;
          else              ((bf16*)Cv)[(size_t)row * N + col] = (bf16)v;
        }
  }
}

// -------- sliding-window GQA flash attention, 4 heads/block, KVBLK=64 -------
__global__ __launch_bounds__(512) void attn_kernel(const bf16* __restrict__ Q,
                                                   const bf16* __restrict__ Kb,
                                                   const bf16* __restrict__ Vt,
                                                   const int* __restrict__ pos,
                                                   const int* __restrict__ cu,
                                                   bf16* __restrict__ O, int T, int B) {
  __shared__ bf16 sK[2][64 * 128];    // 32 KB, chunk^(key&7)
  __shared__ bf16 sV[2][128 * 64];    // 32 KB, chunk^(d&7)
  __shared__ bf16 sP[8][16 * 40];     // 10 KB
  int bid = blockIdx.x;
  int nqb = T >> 6;
  int kvh = bid / nqb;
  int u   = bid % nqb;
  int qb  = (u & 7) * (nqb >> 3) + (u >> 3);   // XCD-contiguous q-ranges
  int q0 = qb * 64;
  int tid = threadIdx.x, lane = tid & 63, w = tid >> 6;
  int hh = w & 3, rh = w >> 2;
  int h = kvh * 4 + hh;
  int li = lane & 15, g = lane >> 4, g8 = g * 8;
  int rb0 = q0 + rh * 32;

  int seq_start = 0, seq_end = T;
  for (int b = 0; b < B; ++b) {
    int a = cu[b], e = cu[b + 1];
    if (q0 >= a && q0 < e) { seq_start = a; seq_end = e; }
  }

  bf16x8 qf[2][4];
  #pragma unroll
  for (int grp = 0; grp < 2; ++grp)
    #pragma unroll
    for (int kd = 0; kd < 4; ++kd)
      qf[grp][kd] = *(const bf16x8*)(Q + (size_t)(rb0 + grp * 16 + li) * HIDDEN
                                     + h * HD + kd * 32 + g8);

  int pq[2][4], pmin[2], pmax[2];
  #pragma unroll
  for (int grp = 0; grp < 2; ++grp) {
    #pragma unroll
    for (int j = 0; j < 4; ++j) pq[grp][j] = pos[rb0 + grp * 16 + g * 4 + j];
    pmin[grp] = pos[rb0 + grp * 16];
    pmax[grp] = pos[rb0 + grp * 16 + 15];
  }

  float lsum[2][4] = {};
  f32x4 acc[2][8] = {};
  int kstart = q0 - WINDOW;
  if (kstart < seq_start) kstart = seq_start;
  int kend = q0 + 64;
  if (kend > seq_end) kend = seq_end;
  const float scale = 0.08838834764831845f;
  int nt = (kend - kstart) >> 6;

#define STAGE(kb_, buf_) { \
  _Pragma("unroll") for (int r = 0; r < 2; ++r) { \
    int n = r * 512 + tid; \
    int krow = n >> 4, kc = (n & 15) ^ (krow & 7); \
    gld16(Kb + (size_t)((kb_) + krow) * (NKV * HD) + kvh * HD + kc * 8, \
          &sK[buf_][(size_t)(r * 512 + (tid & ~63)) * 8]); \
    int vd = n >> 3, vc = (n & 7) ^ (vd & 7); \
    gld16(Vt + (size_t)(kvh * HD + vd) * T + (kb_) + vc * 8, \
          &sV[buf_][(size_t)(r * 512 + (tid & ~63)) * 8]); } }
#define VMW(n) asm volatile("s_waitcnt vmcnt(" #n ")" ::: "memory")

  STAGE(kstart, 0);
  for (int t = 0; t < nt; ++t) {
    int kb0 = kstart + t * 64;
    int cur = t & 1;
    VMW(0);
    barrier_raw();
    if (t + 1 < nt) STAGE(kb0 + 64, cur ^ 1);

    #pragma unroll
    for (int hhalf = 0; hhalf < 2; ++hhalf) {
      int kb = kb0 + hhalf * 32;
      int pkf = pos[kb], pkl = pos[kb + 31];
      int pk0 = pos[kb + li], pk1 = pos[kb + 16 + li];
      #pragma unroll
      for (int grp = 0; grp < 2; ++grp) {
        if (pkf > pmax[grp] || pkl < pmin[grp] - WINDOW) continue;  // wave-uniform
        f32x4 s0v = {0.f, 0.f, 0.f, 0.f}, s1v = {0.f, 0.f, 0.f, 0.f};
        #pragma unroll
        for (int kd = 0; kd < 4; ++kd) {
          int c0 = (kd * 4 + g) ^ (li & 7);
          bf16x8 b0 = *(const bf16x8*)&sK[cur][(hhalf * 32 + li) * 128 + c0 * 8];
          bf16x8 b1 = *(const bf16x8*)&sK[cur][(hhalf * 32 + 16 + li) * 128 + c0 * 8];
          s0v = mfma16(qf[grp][kd], b0, s0v);
          s1v = mfma16(qf[grp][kd], b1, s1v);
        }
        bool interior = (pkl <= pmin[grp]) && (pmax[grp] - pkf <= WINDOW);
        if (interior) {
          #pragma unroll
          for (int j = 0; j < 4; ++j) {
            float p0 = __expf(s0v[j] * scale);
            float p1 = __expf(s1v[j] * scale);
            lsum[grp][j] += p0 + p1;
            sP[w][(g * 4 + j) * 40 + li]      = (bf16)p0;
            sP[w][(g * 4 + j) * 40 + 16 + li] = (bf16)p1;
          }
        } else {
          #pragma unroll
          for (int j = 0; j < 4; ++j) {
            int d0 = pq[grp][j] - pk0, d1 = pq[grp][j] - pk1;
            float p0 = (d0 >= 0 && d0 <= WINDOW) ? __expf(s0v[j] * scale) : 0.f;
            float p1 = (d1 >= 0 && d1 <= WINDOW) ? __expf(s1v[j] * scale) : 0.f;
            lsum[grp][j] += p0 + p1;
            sP[w][(g * 4 + j) * 40 + li]      = (bf16)p0;
            sP[w][(g * 4 + j) * 40 + 16 + li] = (bf16)p1;
          }
        }
        bf16x8 pa = *(const bf16x8*)&sP[w][li * 40 + g8];
        #pragma unroll
        for (int dt = 0; dt < 8; ++dt) {
          int d = dt * 16 + li;
          int vc2 = (hhalf * 4 + g) ^ (d & 7);
          bf16x8 vf = *(const bf16x8*)&sV[cur][d * 64 + vc2 * 8];
          acc[grp][dt] = mfma16(pa, vf, acc[grp][dt]);
        }
      }
    }
  }
#undef STAGE
#undef VMW

  #pragma unroll
  for (int grp = 0; grp < 2; ++grp)
    #pragma unroll
    for (int j = 0; j < 4; ++j) {
      float rs = lsum[grp][j];
      rs += __shfl_xor(rs, 1);
      rs += __shfl_xor(rs, 2);
      rs += __shfl_xor(rs, 4);
      rs += __shfl_xor(rs, 8);
      float invl = 1.0f / rs;
      size_t base = (size_t)(rb0 + grp * 16 + g * 4 + j) * HIDDEN + h * HD;
      #pragma unroll
      for (int dt = 0; dt < 8; ++dt)
        O[base + dt * 16 + li] = (bf16)(acc[grp][dt][j] * invl);
    }
}

// ---------------- launcher --------------------------------------------------
extern "C" void kernel_launch(void* const* d_in, const int* in_sizes, int n_in,
                              void* d_out, int out_size, void* d_ws, size_t ws_size,
                              hipStream_t stream) {
  const float* X  = (const float*)d_in[0];
  const float* qw = (const float*)d_in[1];
  const float* kw = (const float*)d_in[2];
  const float* vw = (const float*)d_in[3];
  const float* ow = (const float*)d_in[4];
  const int* pos = (const int*)d_in[5];
  const int* cu  = (const int*)d_in[6];
  int T = in_sizes[0] / HIDDEN;     // 8192
  int B = in_sizes[6] - 1;          // 4
  float* out = (float*)d_out;

  bf16* ws = (bf16*)d_ws;
  size_t off = 0;
  bf16* Xb    = ws + off; off += (size_t)T * HIDDEN;
  bf16* Qb    = ws + off; off += (size_t)T * HIDDEN;       // Q, then attn out
  bf16* Kb    = ws + off; off += (size_t)T * (NKV * HD);
  bf16* Vt    = ws + off; off += (size_t)T * (NKV * HD);
  bf16* qwT   = ws + off; off += (size_t)HIDDEN * HIDDEN;
  bf16* kvwT  = ws + off; off += (size_t)1024 * HIDDEN;    // [kwT; vwT] stacked
  bf16* owT   = ws + off; off += (size_t)HIDDEN * HIDDEN;

  cast_f32_bf16<<<(T * HIDDEN / 8 + 255) / 256, 256, 0, stream>>>(X, Xb, T * HIDDEN / 8);

  dim3 tb(32, 8);
  transpose_cast2<<<dim3(HIDDEN / 32, HIDDEN / 32, 2), tb, 0, stream>>>(
      qw, qwT, ow, owT, HIDDEN, HIDDEN);
  transpose_cast2<<<dim3(512 / 32, HIDDEN / 32, 2), tb, 0, stream>>>(
      kw, kvwT, vw, kvwT + (size_t)512 * HIDDEN, HIDDEN, 512);

  // Q-projection with fused RoPE (outMode 3), grid 256
  gemm256<<<(T / 256) * (HIDDEN / 256), 512, 0, stream>>>(Xb, qwT, Qb, pos,
                                                          T, HIDDEN, HIDDEN, 3);
  // merged K+V projection (K gets fused RoPE), 512 blocks, BK=64 swizzled
  gemm_bt<<<(T / 128) * (1024 / 128), 256, 0, stream>>>(Xb, kvwT, Kb, Vt, pos,
                                                        T, 1024, HIDDEN, 3);

  // attention: 4 heads per block, KVBLK=64, grid (T/64)*NKV = 512
  attn_kernel<<<(T / 64) * NKV, 512, 0, stream>>>(Qb, Kb, Vt, pos, cu, Qb, T, B);

  // O-projection (fp32 out), grid 256
  gemm256<<<(T / 256) * (HIDDEN / 256), 512, 0, stream>>>(Qb, owT, out, nullptr,
                                                          T, HIDDEN, HIDDEN, 2);
}

// Round 19
// 278.835 us; speedup vs baseline: 1.0482x; 1.0482x over previous
//
#include <hip/hip_runtime.h>
#include <hip/hip_bf16.h>
#include <cstdint>
#include <cstddef>

typedef __bf16 bf16;
typedef __bf16 bf16x2 __attribute__((ext_vector_type(2)));
typedef __bf16 bf16x4 __attribute__((ext_vector_type(4)));
typedef __bf16 bf16x8 __attribute__((ext_vector_type(8)));
typedef float  f32x4  __attribute__((ext_vector_type(4)));

#define HIDDEN 2048
#define NHEADS 16
#define NKV    4
#define HD     128
#define WINDOW 512
#define NLT    -0.14390747054172642f   // -ln(10000)/64

// async global->LDS, 16B per lane; LDS dest is wave-uniform base + lane*16
__device__ __forceinline__ void gld16(const void* g, void* s) {
  __builtin_amdgcn_global_load_lds((const __attribute__((address_space(1))) void*)g,
                                   (__attribute__((address_space(3))) void*)s, 16, 0, 0);
}

__device__ __forceinline__ f32x4 mfma16(bf16x8 a, bf16x8 b, f32x4 c) {
  return __builtin_amdgcn_mfma_f32_16x16x32_bf16(a, b, c, 0, 0, 0);
}

__device__ __forceinline__ void barrier_raw() {
  asm volatile("" ::: "memory");
  __builtin_amdgcn_s_barrier();
  asm volatile("" ::: "memory");
}

// ---------------- cast fp32 -> bf16, 8 elems/thread -------------------------
__global__ __launch_bounds__(256) void cast_f32_bf16(const float* __restrict__ in,
                                                     bf16* __restrict__ out, int n8) {
  int i = blockIdx.x * 256 + threadIdx.x;
  if (i >= n8) return;
  f32x4 a = *(const f32x4*)(in + (size_t)i * 8);
  f32x4 b = *(const f32x4*)(in + (size_t)i * 8 + 4);
  bf16x8 o;
  #pragma unroll
  for (int k = 0; k < 4; ++k) { o[k] = (bf16)a[k]; o[k + 4] = (bf16)b[k]; }
  *(bf16x8*)(out + (size_t)i * 8) = o;
}

// ------- transpose+cast, 2 matrices per launch (blockIdx.z selects) ---------
__global__ __launch_bounds__(256) void transpose_cast2(const float* __restrict__ in0,
                                                       bf16* __restrict__ out0,
                                                       const float* __restrict__ in1,
                                                       bf16* __restrict__ out1,
                                                       int R, int C) {
  const float* in = blockIdx.z ? in1 : in0;
  bf16* out       = blockIdx.z ? out1 : out0;
  __shared__ float tile[32][33];
  int c0 = blockIdx.x * 32, r0 = blockIdx.y * 32;
  int tx = threadIdx.x, ty = threadIdx.y;
  #pragma unroll
  for (int i = 0; i < 4; ++i)
    tile[ty + i * 8][tx] = in[(size_t)(r0 + ty + i * 8) * C + c0 + tx];
  __syncthreads();
  #pragma unroll
  for (int i = 0; i < 4; ++i)
    out[(size_t)(c0 + ty + i * 8) * R + r0 + tx] = (bf16)tile[tx][ty + i * 8];
}

// ===== 128x128 GEMM, BK=64, swizzled LDS (merged K+V projection) ============
__device__ __forceinline__ void stage128x64(const bf16* __restrict__ A,
                                            const bf16* __restrict__ Bt,
                                            bf16* sA, bf16* sB,
                                            int m0, int n0, int K, int kt, int tid) {
  int wb = (tid & ~63) * 8;
  #pragma unroll
  for (int r = 0; r < 4; ++r) {
    int n = r * 256 + tid;                   // chunk id 0..1023
    int row = n >> 3;
    int c = (n & 7) ^ (row & 7);             // inverse-swizzled source chunk
    gld16(A  + (size_t)(m0 + row) * K + (size_t)kt * 64 + c * 8,
          sA + (size_t)(r * 256 * 8) + wb);
    gld16(Bt + (size_t)(n0 + row) * K + (size_t)kt * 64 + c * 8,
          sB + (size_t)(r * 256 * 8) + wb);
  }
}

// outMode: 0 bf16 row-major; 1 bf16 C^T; 2 fp32 row-major;
//          3 merged KV+RoPE: col<512 -> K row-major with RoPE; else V^T
__global__ __launch_bounds__(256) void gemm_bt(const bf16* __restrict__ A,
                                               const bf16* __restrict__ Bt,
                                               void* __restrict__ Cv,
                                               bf16* __restrict__ Vtout,
                                               const int* __restrict__ pos,
                                               int M, int N, int K, int outMode) {
  __shared__ bf16 sA[2][128 * 64];           // 32 KB
  __shared__ bf16 sB[2][128 * 64];           // 32 KB
  int nb = N >> 7;
  int perx = (int)gridDim.x >> 3;            // grid must be a multiple of 8
  int bid0 = (int)blockIdx.x;
  int swzb = (bid0 & 7) * perx + (bid0 >> 3);
  int bm = swzb / nb, bn = swzb % nb;
  int m0 = bm << 7, n0 = bn << 7;
  int tid = threadIdx.x;
  int lane = tid & 63, w = tid >> 6;
  int li = lane & 15, g = lane >> 4;
  int wm = w >> 1, wn = w & 1;
  int swz = li & 7;
  f32x4 acc[4][4] = {};
  int NT = K >> 6;                           // 32

  stage128x64(A, Bt, sA[0], sB[0], m0, n0, K, 0, tid);
  for (int kt = 0; kt < NT; ++kt) {
    int cur = kt & 1;
    asm volatile("s_waitcnt vmcnt(0)" ::: "memory");   // own tile-kt loads
    barrier_raw();                                      // publish to all waves
    if (kt + 1 < NT)
      stage128x64(A, Bt, sA[cur ^ 1], sB[cur ^ 1], m0, n0, K, kt + 1, tid);
    bf16x8 af[4][2], bv[4][2];
    #pragma unroll
    for (int mt = 0; mt < 4; ++mt)
      #pragma unroll
      for (int ks = 0; ks < 2; ++ks)
        af[mt][ks] = *(const bf16x8*)&sA[cur][(wm * 64 + mt * 16 + li) * 64
                                              + ((ks * 4 + g) ^ swz) * 8];
    #pragma unroll
    for (int nt = 0; nt < 4; ++nt)
      #pragma unroll
      for (int ks = 0; ks < 2; ++ks)
        bv[nt][ks] = *(const bf16x8*)&sB[cur][(wn * 64 + nt * 16 + li) * 64
                                              + ((ks * 4 + g) ^ swz) * 8];
    #pragma unroll
    for (int mt = 0; mt < 4; ++mt)
      #pragma unroll
      for (int nt = 0; nt < 4; ++nt)
        #pragma unroll
        for (int ks = 0; ks < 2; ++ks)
          acc[mt][nt] = mfma16(af[mt][ks], bv[nt][ks], acc[mt][nt]);
  }
  if (outMode == 3 && n0 >= 512) {
    // V^T region: j-vectorized 8B stores (row0 multiple of 4 -> aligned)
    #pragma unroll
    for (int mt = 0; mt < 4; ++mt)
      #pragma unroll
      for (int nt = 0; nt < 4; ++nt) {
        int row0 = m0 + wm * 64 + mt * 16 + g * 4;
        int col = n0 + wn * 64 + nt * 16 + li;
        bf16x4 vv;
        #pragma unroll
        for (int j = 0; j < 4; ++j) vv[j] = (bf16)acc[mt][nt][j];
        *(bf16x4*)&Vtout[(size_t)(col - 512) * M + row0] = vv;
      }
  } else if (outMode == 3) {
    // K region with fused RoPE; paired bf16x2 stores (even lanes, 4B)
    #pragma unroll
    for (int mt = 0; mt < 4; ++mt)
      #pragma unroll
      for (int nt = 0; nt < 4; ++nt)
        #pragma unroll
        for (int j = 0; j < 4; ++j) {
          int row = m0 + wm * 64 + mt * 16 + g * 4 + j;
          int col = n0 + wn * 64 + nt * 16 + li;
          float v = acc[mt][nt][j];
          float inv = __expf((float)((col & 127) >> 1) * NLT);
          float ang = (float)pos[row] * inv;
          float s = __sinf(ang), c = __cosf(ang);
          float pv = __shfl_xor(v, 1);
          float outv = (li & 1) ? (pv * s + v * c) : (v * c - pv * s);
          float po = __shfl_xor(outv, 1);
          if (!(lane & 1)) {
            bf16x2 t2; t2[0] = (bf16)outv; t2[1] = (bf16)po;
            *(bf16x2*)&((bf16*)Cv)[(size_t)row * 512 + col] = t2;
          }
        }
  } else {
    #pragma unroll
    for (int mt = 0; mt < 4; ++mt)
      #pragma unroll
      for (int nt = 0; nt < 4; ++nt)
        #pragma unroll
        for (int j = 0; j < 4; ++j) {
          int row = m0 + wm * 64 + mt * 16 + g * 4 + j;
          int col = n0 + wn * 64 + nt * 16 + li;
          float v = acc[mt][nt][j];
          if (outMode == 0)      ((bf16*)Cv)[(size_t)row * N + col] = (bf16)v;
          else if (outMode == 1) ((bf16*)Cv)[(size_t)col * M + row] = (bf16)v;
          else                   ((float*)Cv)[(size_t)row * N + col] = v;
        }
  }
}

// ============== 256x256 8-wave GEMM (round-7 spread-stage schedule) =========
template<int RSP>  // 64 for A halves, 32 for B halves
__device__ __forceinline__ void stage_quad(const bf16* __restrict__ G,
                                           bf16* __restrict__ sbuf,
                                           int grow0, int K, int k0, int half, int tid) {
  int w = tid >> 6, lane = tid & 63;
  int rl = lane >> 3;
  int col = ((lane & 7) ^ rl) * 8;            // inverse-swizzled SOURCE col (rule #21)
  #pragma unroll
  for (int r = 0; r < 2; ++r) {
    int lr0 = r * 64 + w * 8;
    int row0 = (lr0 & (RSP - 1)) + half * RSP + (lr0 / RSP) * 2 * RSP;
    gld16(G + (size_t)(grow0 + row0 + rl) * K + k0 + col,
          sbuf + row0 * 64);
  }
}

// outMode: 0 bf16; 2 fp32; 3 bf16 + fused interleaved RoPE (Q projection)
__global__ __launch_bounds__(512, 2) void gemm256(const bf16* __restrict__ A,
                                                  const bf16* __restrict__ Bt,
                                                  void* __restrict__ Cv,
                                                  const int* __restrict__ pos,
                                                  int M, int N, int K, int outMode) {
  __shared__ bf16 sA[2][256 * 64];
  __shared__ bf16 sB[2][256 * 64];
  int nb = N >> 8;
  int cpx = (int)gridDim.x >> 3;
  int bid = (int)blockIdx.x;
  int swzb = (bid & 7) * cpx + (bid >> 3);
  int bm = swzb / nb, bn = swzb % nb;
  int m0 = bm << 8, n0 = bn << 8;
  int tid = threadIdx.x, lane = tid & 63, w = tid >> 6;
  int li = lane & 15, g = lane >> 4;
  int wm = w >> 2, wn = w & 3;
  int swz = (li & 7);

  f32x4 acc[8][4] = {};
  bf16x8 af[4][2];
  bf16x8 bv[2][2][2];

  int NT = K >> 6;

  stage_quad<64>(A,  sA[0], m0, K, 0, 0, tid);
  stage_quad<32>(Bt, sB[0], n0, K, 0, 0, tid);
  stage_quad<32>(Bt, sB[0], n0, K, 0, 1, tid);
  stage_quad<64>(A,  sA[0], m0, K, 0, 1, tid);

#define VMW(n) asm volatile("s_waitcnt vmcnt(" #n ")" ::: "memory")
#define SBAR() __builtin_amdgcn_sched_barrier(0)
#define LGKM(n) { asm volatile("s_waitcnt lgkmcnt(" #n ")" ::: "memory"); \
  __builtin_amdgcn_sched_barrier(0); }
#define LOAD_A256(mh) { _Pragma("unroll") for (int mf = 0; mf < 4; ++mf) \
  _Pragma("unroll") for (int ks = 0; ks < 2; ++ks) { \
    int row = wm * 128 + (mh) * 64 + mf * 16 + li; \
    af[mf][ks] = *(const bf16x8*)&sA[cur][row * 64 + ((ks * 4 + g) ^ swz) * 8]; } }
#define LOAD_B256(nh) { _Pragma("unroll") for (int nf = 0; nf < 2; ++nf) \
  _Pragma("unroll") for (int ks = 0; ks < 2; ++ks) { \
    int row = wn * 64 + (nh) * 32 + nf * 16 + li; \
    bv[nh][nf][ks] = *(const bf16x8*)&sB[cur][row * 64 + ((ks * 4 + g) ^ swz) * 8]; } }
#define MFMA_PH(mh, nh) { \
  __builtin_amdgcn_s_setprio(1); \
  _Pragma("unroll") for (int mf = 0; mf < 4; ++mf) \
  _Pragma("unroll") for (int nf = 0; nf < 2; ++nf) \
  _Pragma("unroll") for (int ks = 0; ks < 2; ++ks) \
    acc[(mh) * 4 + mf][(nh) * 2 + nf] = \
      mfma16(af[mf][ks], bv[nh][nf][ks], acc[(mh) * 4 + mf][(nh) * 2 + nf]); \
  __builtin_amdgcn_s_setprio(0); }

  int cur = 0;
  for (int t = 0; t < NT; ++t) {
    int nxt = cur ^ 1;
    bool pre = (t + 1 < NT);
    int k1 = (t + 1) << 6;
    VMW(0);
    barrier_raw();
    if (pre) stage_quad<64>(A, sA[nxt], m0, K, k1, 0, tid);
    LOAD_A256(0); LOAD_B256(0);
    SBAR();
    LOAD_B256(1);
    if (pre) stage_quad<32>(Bt, sB[nxt], n0, K, k1, 0, tid);
    LGKM(4);
    MFMA_PH(0, 0);
    if (pre) stage_quad<32>(Bt, sB[nxt], n0, K, k1, 1, tid);
    LGKM(0);
    MFMA_PH(0, 1);
    LOAD_A256(1);
    if (pre) stage_quad<64>(A, sA[nxt], m0, K, k1, 1, tid);
    LGKM(0);
    MFMA_PH(1, 1);
    MFMA_PH(1, 0);
    cur = nxt;
  }
#undef VMW
#undef SBAR
#undef LGKM
#undef LOAD_A256
#undef LOAD_B256
#undef MFMA_PH

  if (outMode == 3) {
    // fused interleaved RoPE; __sinf/__cosf return-by-value (r10 lesson);
    // paired bf16x2 stores (even lanes) avoid 2x write amplification.
    float inv4[4];
    #pragma unroll
    for (int ni = 0; ni < 4; ++ni) {
      int col = n0 + wn * 64 + ni * 16 + li;
      inv4[ni] = __expf((float)((col & 127) >> 1) * NLT);
    }
    #pragma unroll
    for (int mi = 0; mi < 8; ++mi)
      #pragma unroll
      for (int j = 0; j < 4; ++j) {
        int row = m0 + wm * 128 + mi * 16 + g * 4 + j;
        float pr = (float)pos[row];
        #pragma unroll
        for (int ni = 0; ni < 4; ++ni) {
          int col = n0 + wn * 64 + ni * 16 + li;
          float ang = pr * inv4[ni];
          float s = __sinf(ang), c = __cosf(ang);
          float v = acc[mi][ni][j];
          float pv = __shfl_xor(v, 1);
          float outv = (li & 1) ? (pv * s + v * c) : (v * c - pv * s);
          float po = __shfl_xor(outv, 1);
          if (!(lane & 1)) {
            bf16x2 t2; t2[0] = (bf16)outv; t2[1] = (bf16)po;
            *(bf16x2*)&((bf16*)Cv)[(size_t)row * N + col] = t2;
          }
        }
      }
  } else {
    #pragma unroll
    for (int mi = 0; mi < 8; ++mi)
      #pragma unroll
      for (int ni = 0; ni < 4; ++ni)
        #pragma unroll
        for (int j = 0; j < 4; ++j) {
          int row = m0 + wm * 128 + mi * 16 + g * 4 + j;
          int col = n0 + wn * 64 + ni * 16 + li;
          float v = acc[mi][ni][j];
          if (outMode == 2) ((float*)Cv)[(size_t)row * N + col] = v;
          else              ((bf16*)Cv)[(size_t)row * N + col] = (bf16)v;
        }
  }
}

// -------- sliding-window GQA flash attention, 4 heads/block, KVBLK=64 -------
__global__ __launch_bounds__(512) void attn_kernel(const bf16* __restrict__ Q,
                                                   const bf16* __restrict__ Kb,
                                                   const bf16* __restrict__ Vt,
                                                   const int* __restrict__ pos,
                                                   const int* __restrict__ cu,
                                                   bf16* __restrict__ O, int T, int B) {
  __shared__ bf16 sK[2][64 * 128];    // 32 KB, chunk^(key&7)
  __shared__ bf16 sV[2][128 * 64];    // 32 KB, chunk^(d&7)
  __shared__ bf16 sP[8][16 * 40];     // 10 KB
  int bid = blockIdx.x;
  int nqb = T >> 6;
  int kvh = bid / nqb;
  int u   = bid % nqb;
  int qb  = (u & 7) * (nqb >> 3) + (u >> 3);   // XCD-contiguous q-ranges
  int q0 = qb * 64;
  int tid = threadIdx.x, lane = tid & 63, w = tid >> 6;
  int hh = w & 3, rh = w >> 2;
  int h = kvh * 4 + hh;
  int li = lane & 15, g = lane >> 4, g8 = g * 8;
  int rb0 = q0 + rh * 32;

  int seq_start = 0, seq_end = T;
  for (int b = 0; b < B; ++b) {
    int a = cu[b], e = cu[b + 1];
    if (q0 >= a && q0 < e) { seq_start = a; seq_end = e; }
  }

  bf16x8 qf[2][4];
  #pragma unroll
  for (int grp = 0; grp < 2; ++grp)
    #pragma unroll
    for (int kd = 0; kd < 4; ++kd)
      qf[grp][kd] = *(const bf16x8*)(Q + (size_t)(rb0 + grp * 16 + li) * HIDDEN
                                     + h * HD + kd * 32 + g8);

  int pq[2][4], pmin[2], pmax[2];
  #pragma unroll
  for (int grp = 0; grp < 2; ++grp) {
    #pragma unroll
    for (int j = 0; j < 4; ++j) pq[grp][j] = pos[rb0 + grp * 16 + g * 4 + j];
    pmin[grp] = pos[rb0 + grp * 16];
    pmax[grp] = pos[rb0 + grp * 16 + 15];
  }

  float lsum[2][4] = {};
  f32x4 acc[2][8] = {};
  int kstart = q0 - WINDOW;
  if (kstart < seq_start) kstart = seq_start;
  int kend = q0 + 64;
  if (kend > seq_end) kend = seq_end;
  const float scale = 0.08838834764831845f;
  int nt = (kend - kstart) >> 6;

#define STAGE(kb_, buf_) { \
  _Pragma("unroll") for (int r = 0; r < 2; ++r) { \
    int n = r * 512 + tid; \
    int krow = n >> 4, kc = (n & 15) ^ (krow & 7); \
    gld16(Kb + (size_t)((kb_) + krow) * (NKV * HD) + kvh * HD + kc * 8, \
          &sK[buf_][(size_t)(r * 512 + (tid & ~63)) * 8]); \
    int vd = n >> 3, vc = (n & 7) ^ (vd & 7); \
    gld16(Vt + (size_t)(kvh * HD + vd) * T + (kb_) + vc * 8, \
          &sV[buf_][(size_t)(r * 512 + (tid & ~63)) * 8]); } }
#define VMW(n) asm volatile("s_waitcnt vmcnt(" #n ")" ::: "memory")

  STAGE(kstart, 0);
  for (int t = 0; t < nt; ++t) {
    int kb0 = kstart + t * 64;
    int cur = t & 1;
    VMW(0);
    barrier_raw();
    if (t + 1 < nt) STAGE(kb0 + 64, cur ^ 1);

    #pragma unroll
    for (int hhalf = 0; hhalf < 2; ++hhalf) {
      int kb = kb0 + hhalf * 32;
      int pkf = pos[kb], pkl = pos[kb + 31];
      int pk0 = pos[kb + li], pk1 = pos[kb + 16 + li];
      #pragma unroll
      for (int grp = 0; grp < 2; ++grp) {
        if (pkf > pmax[grp] || pkl < pmin[grp] - WINDOW) continue;  // wave-uniform
        f32x4 s0v = {0.f, 0.f, 0.f, 0.f}, s1v = {0.f, 0.f, 0.f, 0.f};
        #pragma unroll
        for (int kd = 0; kd < 4; ++kd) {
          int c0 = (kd * 4 + g) ^ (li & 7);
          bf16x8 b0 = *(const bf16x8*)&sK[cur][(hhalf * 32 + li) * 128 + c0 * 8];
          bf16x8 b1 = *(const bf16x8*)&sK[cur][(hhalf * 32 + 16 + li) * 128 + c0 * 8];
          s0v = mfma16(qf[grp][kd], b0, s0v);
          s1v = mfma16(qf[grp][kd], b1, s1v);
        }
        bool interior = (pkl <= pmin[grp]) && (pmax[grp] - pkf <= WINDOW);
        if (interior) {
          #pragma unroll
          for (int j = 0; j < 4; ++j) {
            float p0 = __expf(s0v[j] * scale);
            float p1 = __expf(s1v[j] * scale);
            lsum[grp][j] += p0 + p1;
            sP[w][(g * 4 + j) * 40 + li]      = (bf16)p0;
            sP[w][(g * 4 + j) * 40 + 16 + li] = (bf16)p1;
          }
        } else {
          #pragma unroll
          for (int j = 0; j < 4; ++j) {
            int d0 = pq[grp][j] - pk0, d1 = pq[grp][j] - pk1;
            float p0 = (d0 >= 0 && d0 <= WINDOW) ? __expf(s0v[j] * scale) : 0.f;
            float p1 = (d1 >= 0 && d1 <= WINDOW) ? __expf(s1v[j] * scale) : 0.f;
            lsum[grp][j] += p0 + p1;
            sP[w][(g * 4 + j) * 40 + li]      = (bf16)p0;
            sP[w][(g * 4 + j) * 40 + 16 + li] = (bf16)p1;
          }
        }
        bf16x8 pa = *(const bf16x8*)&sP[w][li * 40 + g8];
        #pragma unroll
        for (int dt = 0; dt < 8; ++dt) {
          int d = dt * 16 + li;
          int vc2 = (hhalf * 4 + g) ^ (d & 7);
          bf16x8 vf = *(const bf16x8*)&sV[cur][d * 64 + vc2 * 8];
          acc[grp][dt] = mfma16(pa, vf, acc[grp][dt]);
        }
      }
    }
  }
#undef STAGE
#undef VMW

  #pragma unroll
  for (int grp = 0; grp < 2; ++grp)
    #pragma unroll
    for (int j = 0; j < 4; ++j) {
      float rs = lsum[grp][j];
      rs += __shfl_xor(rs, 1);
      rs += __shfl_xor(rs, 2);
      rs += __shfl_xor(rs, 4);
      rs += __shfl_xor(rs, 8);
      float invl = 1.0f / rs;
      size_t base = (size_t)(rb0 + grp * 16 + g * 4 + j) * HIDDEN + h * HD;
      #pragma unroll
      for (int dt = 0; dt < 8; ++dt)
        O[base + dt * 16 + li] = (bf16)(acc[grp][dt][j] * invl);
    }
}

// ---------------- launcher --------------------------------------------------
extern "C" void kernel_launch(void* const* d_in, const int* in_sizes, int n_in,
                              void* d_out, int out_size, void* d_ws, size_t ws_size,
                              hipStream_t stream) {
  const float* X  = (const float*)d_in[0];
  const float* qw = (const float*)d_in[1];
  const float* kw = (const float*)d_in[2];
  const float* vw = (const float*)d_in[3];
  const float* ow = (const float*)d_in[4];
  const int* pos = (const int*)d_in[5];
  const int* cu  = (const int*)d_in[6];
  int T = in_sizes[0] / HIDDEN;     // 8192
  int B = in_sizes[6] - 1;          // 4
  float* out = (float*)d_out;

  bf16* ws = (bf16*)d_ws;
  size_t off = 0;
  bf16* Xb    = ws + off; off += (size_t)T * HIDDEN;
  bf16* Qb    = ws + off; off += (size_t)T * HIDDEN;       // Q, then attn out
  bf16* Kb    = ws + off; off += (size_t)T * (NKV * HD);
  bf16* Vt    = ws + off; off += (size_t)T * (NKV * HD);
  bf16* qwT   = ws + off; off += (size_t)HIDDEN * HIDDEN;
  bf16* kvwT  = ws + off; off += (size_t)1024 * HIDDEN;    // [kwT; vwT] stacked
  bf16* owT   = ws + off; off += (size_t)HIDDEN * HIDDEN;

  cast_f32_bf16<<<(T * HIDDEN / 8 + 255) / 256, 256, 0, stream>>>(X, Xb, T * HIDDEN / 8);

  dim3 tb(32, 8);
  transpose_cast2<<<dim3(HIDDEN / 32, HIDDEN / 32, 2), tb, 0, stream>>>(
      qw, qwT, ow, owT, HIDDEN, HIDDEN);
  transpose_cast2<<<dim3(512 / 32, HIDDEN / 32, 2), tb, 0, stream>>>(
      kw, kvwT, vw, kvwT + (size_t)512 * HIDDEN, HIDDEN, 512);

  // Q-projection with fused RoPE (outMode 3), grid 256
  gemm256<<<(T / 256) * (HIDDEN / 256), 512, 0, stream>>>(Xb, qwT, Qb, pos,
                                                          T, HIDDEN, HIDDEN, 3);
  // merged K+V projection (K gets fused RoPE), 512 blocks, BK=64 swizzled
  gemm_bt<<<(T / 128) * (1024 / 128), 256, 0, stream>>>(Xb, kvwT, Kb, Vt, pos,
                                                        T, 1024, HIDDEN, 3);

  // attention: 4 heads per block, KVBLK=64, grid (T/64)*NKV = 512
  attn_kernel<<<(T / 64) * NKV, 512, 0, stream>>>(Qb, Kb, Vt, pos, cu, Qb, T, B);

  // O-projection (fp32 out), grid 256
  gemm256<<<(T / 256) * (HIDDEN / 256), 512, 0, stream>>>(Qb, owT, out, nullptr,
                                                          T, HIDDEN, HIDDEN, 2);
}